// Round 4
// baseline (29.756 us; speedup 1.0000x reference)
//
#include <hip/hip_runtime.h>

// out[i] = A_source[i] + b2 + sum_j W2[j] * tanh(W1[j][0]*c_target[i] + W1[j][1]*wavelength[i] + b1[j])
// (W1[j][2] multiplies a zero; c_source is unused by the reference.)
//
// tanh(z) = 1 - 2/(exp2(z*2/ln2)+1), folded:
//   s = (A + b2 + sum_j W2[j]) + sum_j (-2*W2[j]) * rcp(exp2(z')+1)
// One v_exp_f32 + one v_rcp_f32 per hidden unit (round-1 was VALU-bound on
// the IEEE div sequence; fixed in round 2: 45->28 us).
//
// Round 4: 2 float4 per thread (32B/lane contiguous, 6 loads in flight),
// nontemporal stores via native ext_vector float4 (HIP_vector_type rejected
// by the builtin — round-3 compile error).

#define HGEO 8

typedef float nfloat4 __attribute__((ext_vector_type(4)));

__global__ __launch_bounds__(256) void geodesic_kernel(
    const float4* __restrict__ c_target,
    const float4* __restrict__ wavelength,
    const float4* __restrict__ A_source,
    const float* __restrict__ W1,   // [8][3] row-major
    const float* __restrict__ b1,   // [8]
    const float* __restrict__ W2,   // [8]
    const float* __restrict__ b2,   // [1]
    float4* __restrict__ out,
    int n4)
{
    const float K = 2.885390081777927f;  // 2/ln(2)

    float wa[HGEO], wb[HGEO], bb[HGEO], wo2[HGEO];
    float s0 = b2[0];
#pragma unroll
    for (int j = 0; j < HGEO; ++j) {
        wa[j]  = W1[j * 3 + 0] * K;
        wb[j]  = W1[j * 3 + 1] * K;
        bb[j]  = b1[j] * K;
        float wo = W2[j];
        wo2[j] = -2.0f * wo;
        s0 += wo;
    }

    const int base = (blockIdx.x * blockDim.x + threadIdx.x) * 2;
    if (base + 1 >= n4) return;

    // Two adjacent float4s per stream: 32B contiguous per lane.
    float4 c0 = c_target[base],   c1 = c_target[base + 1];
    float4 w0 = wavelength[base], w1 = wavelength[base + 1];
    float4 a0 = A_source[base],   a1 = A_source[base + 1];

    const float cv[8] = {c0.x, c0.y, c0.z, c0.w, c1.x, c1.y, c1.z, c1.w};
    const float wv[8] = {w0.x, w0.y, w0.z, w0.w, w1.x, w1.y, w1.z, w1.w};
    const float av[8] = {a0.x, a0.y, a0.z, a0.w, a1.x, a1.y, a1.z, a1.w};
    float ov[8];

#pragma unroll
    for (int k = 0; k < 8; ++k) {
        float s = av[k] + s0;
#pragma unroll
        for (int j = 0; j < HGEO; ++j) {
            float z = fmaf(wa[j], cv[k], fmaf(wb[j], wv[k], bb[j]));
            float e = exp2f(z);                        // one v_exp_f32
            float r = __builtin_amdgcn_rcpf(e + 1.0f); // one v_rcp_f32
            s = fmaf(wo2[j], r, s);
        }
        ov[k] = s;
    }

    nfloat4 o0 = {ov[0], ov[1], ov[2], ov[3]};
    nfloat4 o1 = {ov[4], ov[5], ov[6], ov[7]};
    nfloat4* outv = (nfloat4*)out;
    __builtin_nontemporal_store(o0, &outv[base]);
    __builtin_nontemporal_store(o1, &outv[base + 1]);
}

extern "C" void kernel_launch(void* const* d_in, const int* in_sizes, int n_in,
                              void* d_out, int out_size, void* d_ws, size_t ws_size,
                              hipStream_t stream) {
    // Input order per setup_inputs(): c_source, c_target, wavelength, A_source, W1, b1, W2, b2
    const float4* c_target   = (const float4*)d_in[1];
    const float4* wavelength = (const float4*)d_in[2];
    const float4* A_source   = (const float4*)d_in[3];
    const float*  W1 = (const float*)d_in[4];
    const float*  b1 = (const float*)d_in[5];
    const float*  W2 = (const float*)d_in[6];
    const float*  b2 = (const float*)d_in[7];
    float4* out = (float4*)d_out;

    const int n4 = out_size / 4;                 // 2097152 float4s
    const int threads = 256;
    const int blocks = (n4 / 2 + threads - 1) / threads;  // 4096 — two float4 per thread
    geodesic_kernel<<<blocks, threads, 0, stream>>>(
        c_target, wavelength, A_source, W1, b1, W2, b2, out, n4);
}